// Round 8
// baseline (214.532 us; speedup 1.0000x reference)
//
#include <hip/hip_runtime.h>

#define BATCH 384
#define DIM   1024
#define MARGIN_F 0.5f
#define EPS_F 1e-16f
#define N2 (BATCH * BATCH)
#define NTILE 12                 // 384/32
#define NUT   78                 // upper-triangle tiles (12*13/2)
#define SPLIT 8                  // K slices
#define KSLICE (DIM / SPLIT)     // 128
#define GRID_BLKS (NUT * SPLIT)  // 624

// ---------------------------------------------------------------------------
// Hand-rolled grid barrier (normal launch, co-resident grid).
// Release: __threadfence + agent-scope RMW; acquire: agent-scope load spin.
// Counters are zeroed by a memset node each call (ws is poisoned, not reset).
// ---------------------------------------------------------------------------
__device__ __forceinline__ void grid_barrier(unsigned* ctr) {
    __syncthreads();
    if (threadIdx.x == 0) {
        __threadfence();   // release all prior global stores (device scope)
        __hip_atomic_fetch_add(ctr, 1u, __ATOMIC_ACQ_REL, __HIP_MEMORY_SCOPE_AGENT);
        while (__hip_atomic_load(ctr, __ATOMIC_ACQUIRE, __HIP_MEMORY_SCOPE_AGENT)
               < (unsigned)GRID_BLKS) {
            __builtin_amdgcn_s_sleep(2);
        }
        __threadfence();   // acquire side
    }
    __syncthreads();
}

// ---------------------------------------------------------------------------
// Single fused kernel, phase bodies verbatim from round 7.
// Phase 1 (624 blocks): upper-tri split-K gram tiles + mirror store + ddiag.
// Phase 2 (blocks 0..383): per-anchor triplet reduction -> part[].
// Phase 3 (block 0, wave 0): double-precision finalize -> out[0..2].
// ---------------------------------------------------------------------------
__global__ __launch_bounds__(256) void fused_kernel(const float* __restrict__ E,
                                                    const int* __restrict__ labels,
                                                    float* __restrict__ dpart,
                                                    float* __restrict__ ddiag,
                                                    float* __restrict__ part,
                                                    float* __restrict__ out,
                                                    unsigned* __restrict__ ctr) {
    __shared__ float As[32][36];
    __shared__ float Bs[32][36];
    __shared__ float drow[BATCH];
    __shared__ int   lab[BATCH];
    __shared__ int   plist[BATCH];
    __shared__ int   npos_s;
    __shared__ float ssum[4];
    __shared__ int   spos[4];
    __shared__ int   sval[4];

    const int t = threadIdx.x;

    // ---------------- phase 1: gram tiles (verbatim R7 dist body) ----------
    {
        const int bid = blockIdx.x;
        const int z   = bid / NUT;
        int tt        = bid % NUT;
        int by = 0;
        while (tt >= NTILE - by) { tt -= NTILE - by; ++by; }
        const int bx = by + tt;          // bx >= by

        const int tx = t & 15;
        const int ty = t >> 4;
        const int rb = by * 32;
        const int cb = bx * 32;
        const int kb = z * KSLICE;

        float acc00 = 0.f, acc01 = 0.f, acc10 = 0.f, acc11 = 0.f;

        const int lr = t >> 3;           // 0..31
        const int lc = (t & 7) * 4;      // 0,4,...,28

        for (int k0 = 0; k0 < KSLICE; k0 += 32) {
            *(float4*)&As[lr][lc] = *(const float4*)&E[(size_t)(rb + lr) * DIM + kb + k0 + lc];
            *(float4*)&Bs[lr][lc] = *(const float4*)&E[(size_t)(cb + lr) * DIM + kb + k0 + lc];
            __syncthreads();

#pragma unroll
            for (int k = 0; k < 32; k += 4) {
                float4 a0 = *(const float4*)&As[ty][k];
                float4 a1 = *(const float4*)&As[ty + 16][k];
                float4 b0 = *(const float4*)&Bs[tx][k];
                float4 b1 = *(const float4*)&Bs[tx + 16][k];
                acc00 += a0.x * b0.x + a0.y * b0.y + a0.z * b0.z + a0.w * b0.w;
                acc01 += a0.x * b1.x + a0.y * b1.y + a0.z * b1.z + a0.w * b1.w;
                acc10 += a1.x * b0.x + a1.y * b0.y + a1.z * b0.z + a1.w * b0.w;
                acc11 += a1.x * b1.x + a1.y * b1.y + a1.z * b1.z + a1.w * b1.w;
            }
            __syncthreads();
        }

        float* dst = dpart + (size_t)z * N2;
        const int r0 = rb + ty, r1 = rb + ty + 16;
        const int c0 = cb + tx, c1 = cb + tx + 16;
        dst[(size_t)r0 * BATCH + c0] = acc00;
        dst[(size_t)r0 * BATCH + c1] = acc01;
        dst[(size_t)r1 * BATCH + c0] = acc10;
        dst[(size_t)r1 * BATCH + c1] = acc11;

        if (bx != by) {   // mirror store; bit-identical (a.b == b.a)
            dst[(size_t)c0 * BATCH + r0] = acc00;
            dst[(size_t)c1 * BATCH + r0] = acc01;
            dst[(size_t)c0 * BATCH + r1] = acc10;
            dst[(size_t)c1 * BATCH + r1] = acc11;
        }

        if (bx == by && tx == ty) {
            ddiag[z * BATCH + r0] = acc00;
            ddiag[z * BATCH + r1] = acc11;
        }
    }

    grid_barrier(&ctr[0]);

    // ---------------- phase 2: triplet reduction (verbatim R7 body) --------
    if (blockIdx.x < BATCH) {
        const int a = blockIdx.x;

        float da = 0.f;
#pragma unroll
        for (int z = 0; z < SPLIT; ++z) da += ddiag[z * BATCH + a];

        for (int i = t; i < BATCH; i += 256) {
            float row = 0.f, di = 0.f;
#pragma unroll
            for (int z = 0; z < SPLIT; ++z) {
                row += dpart[(size_t)z * N2 + (size_t)a * BATCH + i];
                di  += ddiag[z * BATCH + i];
            }
            const float s = da + di - 2.f * row;   // exactly 0.0 at i==a
            drow[i] = s > 0.f ? sqrtf(s) : 0.f;
            lab[i]  = labels[i];
        }
        __syncthreads();

        const int la = lab[a];

        if (t < 64) {   // deterministic positives-list build on wave 0
            int cnt = 0;
#pragma unroll
            for (int c = 0; c < BATCH; c += 64) {
                const int i = c + t;
                const bool f = (lab[i] == la) && (i != a);
                const unsigned long long m = __ballot(f);
                if (f) {
                    const int off = __popcll(m & ((1ull << t) - 1ull));
                    plist[cnt + off] = i;
                }
                cnt += __popcll(m);
            }
            if (t == 0) npos_s = cnt;
        }
        __syncthreads();

        const int npos = npos_s;
        float sum = 0.f;
        int   pos = 0, valid = 0;

        for (int n = t; n < BATCH; n += 256) {
            if (lab[n] != la) {
                const float dan = drow[n];
                valid += npos;
                for (int q = 0; q < npos; ++q) {
                    float tl = drow[plist[q]] - dan + MARGIN_F;
                    if (tl > EPS_F) { sum += tl; ++pos; }
                }
            }
        }

#pragma unroll
        for (int off = 32; off > 0; off >>= 1) {
            sum   += __shfl_down(sum, off);
            pos   += __shfl_down(pos, off);
            valid += __shfl_down(valid, off);
        }
        const int wave = t >> 6, lane = t & 63;
        if (lane == 0) { ssum[wave] = sum; spos[wave] = pos; sval[wave] = valid; }
        __syncthreads();

        if (t == 0) {
            float s = 0.f; int p2 = 0, v = 0;
#pragma unroll
            for (int w = 0; w < 4; ++w) { s += ssum[w]; p2 += spos[w]; v += sval[w]; }
            part[a]             = s;
            part[BATCH + a]     = (float)p2;
            part[2 * BATCH + a] = (float)v;
        }
    }

    grid_barrier(&ctr[1]);

    // ---------------- phase 3: finalize (block 0, wave 0, verbatim) --------
    if (blockIdx.x == 0 && t < 64) {
        const int lane = t;
        double s = 0.0, p = 0.0, v = 0.0;
#pragma unroll
        for (int c = 0; c < BATCH; c += 64) {
            s += (double)part[c + lane];
            p += (double)part[BATCH + c + lane];
            v += (double)part[2 * BATCH + c + lane];
        }
#pragma unroll
        for (int off = 32; off > 0; off >>= 1) {
            s += __shfl_down(s, off);
            p += __shfl_down(p, off);
            v += __shfl_down(v, off);
        }
        if (lane == 0) {
            out[0] = (float)(s / (p + 1e-16));
            out[1] = (float)p;
            out[2] = (float)v;
        }
    }
}

extern "C" void kernel_launch(void* const* d_in, const int* in_sizes, int n_in,
                              void* d_out, int out_size, void* d_ws, size_t ws_size,
                              hipStream_t stream) {
    const int*   labels = (const int*)d_in[0];
    const float* E      = (const float*)d_in[1];
    float* out = (float*)d_out;

    // ws: [ctr: 2 u32 @0][part @256: 3*384 f][ddiag @8192: 8*384 f][dpart @24576]
    unsigned* ctr  = (unsigned*)d_ws;
    float* part    = (float*)((char*)d_ws + 256);
    float* ddiag   = (float*)((char*)d_ws + 8192);
    float* dpart   = (float*)((char*)d_ws + 24576);

    hipMemsetAsync(ctr, 0, 2 * sizeof(unsigned), stream);
    fused_kernel<<<GRID_BLKS, 256, 0, stream>>>(E, labels, dpart, ddiag, part, out, ctr);
}

// Round 9
// 28.068 us; speedup vs baseline: 7.6433x; 7.6433x over previous
//
#include <hip/hip_runtime.h>

#define BATCH 384
#define DIM   1024
#define MARGIN_F 0.5f
#define EPS_F 1e-16f
#define N2 (BATCH * BATCH)
#define NTILE 12                 // 384/32
#define NUT   78                 // upper-triangle tiles (12*13/2)
#define SPLIT 8                  // K slices
#define KSLICE (DIM / SPLIT)     // 128
#define DIST_BLKS (NUT * SPLIT)  // 624

// ---------------------------------------------------------------------------
// Kernel 1: split-K partial gram, upper-triangle tiles, linear 624-block grid
// (no early-return blocks). Bodies verbatim from round 7. Block 0 zeroes the
// last-block counter (kernel-boundary ordering makes it visible to kernel 2).
// ---------------------------------------------------------------------------
__global__ __launch_bounds__(256) void dist_kernel(const float* __restrict__ E,
                                                   float* __restrict__ dpart,
                                                   float* __restrict__ ddiag,
                                                   unsigned* __restrict__ ctr) {
    if (blockIdx.x == 0 && threadIdx.x == 0) *ctr = 0u;

    __shared__ float As[32][36];
    __shared__ float Bs[32][36];

    const int bid = blockIdx.x;
    const int z   = bid / NUT;
    int tt        = bid % NUT;
    int by = 0;
    while (tt >= NTILE - by) { tt -= NTILE - by; ++by; }
    const int bx = by + tt;          // bx >= by

    const int tx = threadIdx.x & 15;
    const int ty = threadIdx.x >> 4;
    const int rb = by * 32;
    const int cb = bx * 32;
    const int kb = z * KSLICE;

    float acc00 = 0.f, acc01 = 0.f, acc10 = 0.f, acc11 = 0.f;

    const int lr = threadIdx.x >> 3;        // 0..31 row within tile
    const int lc = (threadIdx.x & 7) * 4;   // 0,4,...,28

    for (int k0 = 0; k0 < KSLICE; k0 += 32) {
        *(float4*)&As[lr][lc] = *(const float4*)&E[(size_t)(rb + lr) * DIM + kb + k0 + lc];
        *(float4*)&Bs[lr][lc] = *(const float4*)&E[(size_t)(cb + lr) * DIM + kb + k0 + lc];
        __syncthreads();

#pragma unroll
        for (int k = 0; k < 32; k += 4) {
            float4 a0 = *(const float4*)&As[ty][k];
            float4 a1 = *(const float4*)&As[ty + 16][k];
            float4 b0 = *(const float4*)&Bs[tx][k];
            float4 b1 = *(const float4*)&Bs[tx + 16][k];
            acc00 += a0.x * b0.x + a0.y * b0.y + a0.z * b0.z + a0.w * b0.w;
            acc01 += a0.x * b1.x + a0.y * b1.y + a0.z * b1.z + a0.w * b1.w;
            acc10 += a1.x * b0.x + a1.y * b0.y + a1.z * b0.z + a1.w * b0.w;
            acc11 += a1.x * b1.x + a1.y * b1.y + a1.z * b1.z + a1.w * b1.w;
        }
        __syncthreads();
    }

    float* dst = dpart + (size_t)z * N2;
    const int r0 = rb + ty, r1 = rb + ty + 16;
    const int c0 = cb + tx, c1 = cb + tx + 16;
    dst[(size_t)r0 * BATCH + c0] = acc00;
    dst[(size_t)r0 * BATCH + c1] = acc01;
    dst[(size_t)r1 * BATCH + c0] = acc10;
    dst[(size_t)r1 * BATCH + c1] = acc11;

    if (bx != by) {   // mirror store (transposed); bit-identical values
        dst[(size_t)c0 * BATCH + r0] = acc00;
        dst[(size_t)c1 * BATCH + r0] = acc01;
        dst[(size_t)c0 * BATCH + r1] = acc10;
        dst[(size_t)c1 * BATCH + r1] = acc11;
    }

    if (bx == by && tx == ty) {   // compact diagonal partials
        ddiag[z * BATCH + r0] = acc00;
        ddiag[z * BATCH + r1] = acc11;
    }
}

// ---------------------------------------------------------------------------
// Kernel 2: per-anchor triplet reduction (verbatim R7) + last-block finalize.
// No spinning: atomicAdd's return value identifies the last block; finalize
// sums part[] in fixed index order -> deterministic regardless of which
// block runs it.
// ---------------------------------------------------------------------------
__global__ __launch_bounds__(256) void triplet_kernel(const float* __restrict__ dpart,
                                                      const float* __restrict__ ddiag,
                                                      const int* __restrict__ labels,
                                                      float* __restrict__ part,
                                                      unsigned* __restrict__ ctr,
                                                      float* __restrict__ out) {
    __shared__ float drow[BATCH];
    __shared__ int   lab[BATCH];
    __shared__ int   plist[BATCH];
    __shared__ int   npos_s;
    __shared__ float ssum[4];
    __shared__ int   spos[4];
    __shared__ int   sval[4];
    __shared__ int   lastFlag;

    const int t = threadIdx.x;
    const int a = blockIdx.x;

    float da = 0.f;
#pragma unroll
    for (int z = 0; z < SPLIT; ++z) da += ddiag[z * BATCH + a];

    for (int i = t; i < BATCH; i += 256) {
        float row = 0.f, di = 0.f;
#pragma unroll
        for (int z = 0; z < SPLIT; ++z) {
            row += dpart[(size_t)z * N2 + (size_t)a * BATCH + i];
            di  += ddiag[z * BATCH + i];
        }
        const float s = da + di - 2.f * row;   // exactly 0.0 at i==a
        drow[i] = s > 0.f ? sqrtf(s) : 0.f;
        lab[i]  = labels[i];
    }
    __syncthreads();

    const int la = lab[a];

    // deterministic positives-list build on wave 0
    if (t < 64) {
        int cnt = 0;
#pragma unroll
        for (int c = 0; c < BATCH; c += 64) {
            const int i = c + t;
            const bool f = (lab[i] == la) && (i != a);
            const unsigned long long m = __ballot(f);
            if (f) {
                const int off = __popcll(m & ((1ull << t) - 1ull));
                plist[cnt + off] = i;
            }
            cnt += __popcll(m);
        }
        if (t == 0) npos_s = cnt;
    }
    __syncthreads();

    const int npos = npos_s;
    float sum = 0.f;
    int   pos = 0, valid = 0;

    for (int n = t; n < BATCH; n += 256) {
        if (lab[n] != la) {
            const float dan = drow[n];
            valid += npos;
            for (int q = 0; q < npos; ++q) {
                float tl = drow[plist[q]] - dan + MARGIN_F;
                if (tl > EPS_F) { sum += tl; ++pos; }
            }
        }
    }

#pragma unroll
    for (int off = 32; off > 0; off >>= 1) {
        sum   += __shfl_down(sum, off);
        pos   += __shfl_down(pos, off);
        valid += __shfl_down(valid, off);
    }
    const int wave = t >> 6, lane = t & 63;
    if (lane == 0) { ssum[wave] = sum; spos[wave] = pos; sval[wave] = valid; }
    __syncthreads();

    if (t == 0) {
        float s = 0.f; int p2 = 0, v = 0;
#pragma unroll
        for (int w = 0; w < 4; ++w) { s += ssum[w]; p2 += spos[w]; v += sval[w]; }
        part[a]             = s;
        part[BATCH + a]     = (float)p2;
        part[2 * BATCH + a] = (float)v;
        __threadfence();   // release part[] (device scope)
        const unsigned old = atomicAdd(ctr, 1u);   // device-scope by default
        lastFlag = (old == (unsigned)(BATCH - 1));
    }
    __syncthreads();

    // last block: finalize (fixed summation order -> deterministic)
    if (lastFlag && t < 64) {
        __threadfence();   // acquire all part[] writes
        const int lane64 = t;
        double s = 0.0, p = 0.0, v = 0.0;
#pragma unroll
        for (int c = 0; c < BATCH; c += 64) {
            s += (double)part[c + lane64];
            p += (double)part[BATCH + c + lane64];
            v += (double)part[2 * BATCH + c + lane64];
        }
#pragma unroll
        for (int off = 32; off > 0; off >>= 1) {
            s += __shfl_down(s, off);
            p += __shfl_down(p, off);
            v += __shfl_down(v, off);
        }
        if (lane64 == 0) {
            out[0] = (float)(s / (p + 1e-16));
            out[1] = (float)p;
            out[2] = (float)v;
        }
    }
}

extern "C" void kernel_launch(void* const* d_in, const int* in_sizes, int n_in,
                              void* d_out, int out_size, void* d_ws, size_t ws_size,
                              hipStream_t stream) {
    const int*   labels = (const int*)d_in[0];
    const float* E      = (const float*)d_in[1];
    float* out = (float*)d_out;

    // ws: [ctr @0][part @256: 3*384 f][ddiag @8192: 8*384 f][dpart @24576: 8*N2 f]
    unsigned* ctr  = (unsigned*)d_ws;
    float* part    = (float*)((char*)d_ws + 256);
    float* ddiag   = (float*)((char*)d_ws + 8192);
    float* dpart   = (float*)((char*)d_ws + 24576);

    dist_kernel<<<DIST_BLKS, 256, 0, stream>>>(E, dpart, ddiag, ctr);
    triplet_kernel<<<BATCH, 256, 0, stream>>>(dpart, ddiag, labels, part, ctr, out);
}